// Round 1
// baseline (228.422 us; speedup 1.0000x reference)
//
#include <hip/hip_runtime.h>
#include <hip/hip_bf16.h>

// FMICLLoss: out = -mean(s_pos) + ALPHA * ( sum_{i!=j} exp(-d2_ij/2) / (N(N-1)) + EPS )
// N=8192, D=256, SIGMA=1 (inv2s2=0.5), ALPHA=1.5, EPS=1e-8, NORM_EPS=1e-12.

#define N_ROWS 8192
#define DIM    256

typedef __attribute__((ext_vector_type(8))) short short8;
typedef __attribute__((ext_vector_type(4))) float f32x4;

__device__ inline unsigned short f2bf(float f) {
    unsigned u = __float_as_uint(f);
    unsigned r = u + 0x7FFF + ((u >> 16) & 1);   // round-to-nearest-even
    return (unsigned short)(r >> 16);
}

// ---------------------------------------------------------------------------
// Kernel 1: row-normalize z1,z2; write z1n (bf16) + sq[i]; accumulate sum s_pos.
// One wave per row (4 rows / 256-thread block).
// ---------------------------------------------------------------------------
__global__ __launch_bounds__(256) void norm_kernel(
    const float* __restrict__ z1, const float* __restrict__ z2,
    unsigned short* __restrict__ z1n, float* __restrict__ sq,
    double* __restrict__ acc /* acc[0]=neg_sum, acc[1]=spos_sum */) {

    int row  = blockIdx.x * 4 + (threadIdx.x >> 6);
    int lane = threadIdx.x & 63;

    const float4 a = *(const float4*)(z1 + (size_t)row * DIM + lane * 4);
    const float4 b = *(const float4*)(z2 + (size_t)row * DIM + lane * 4);

    float s1 = a.x*a.x + a.y*a.y + a.z*a.z + a.w*a.w;
    float s2 = b.x*b.x + b.y*b.y + b.z*b.z + b.w*b.w;
    #pragma unroll
    for (int off = 32; off; off >>= 1) {
        s1 += __shfl_xor(s1, off);
        s2 += __shfl_xor(s2, off);
    }
    float m1 = fmaxf(sqrtf(s1), 1e-12f);
    float m2 = fmaxf(sqrtf(s2), 1e-12f);

    float4 an = make_float4(a.x/m1, a.y/m1, a.z/m1, a.w/m1);
    float4 bn = make_float4(b.x/m2, b.y/m2, b.z/m2, b.w/m2);

    // positive-pair distance
    float dx = an.x - bn.x, dy = an.y - bn.y, dz = an.z - bn.z, dw = an.w - bn.w;
    float dp = dx*dx + dy*dy + dz*dz + dw*dw;
    #pragma unroll
    for (int off = 32; off; off >>= 1) dp += __shfl_xor(dp, off);

    // write bf16 normalized z1 row (8B per lane)
    uint2 pk;
    pk.x = (unsigned)f2bf(an.x) | ((unsigned)f2bf(an.y) << 16);
    pk.y = (unsigned)f2bf(an.z) | ((unsigned)f2bf(an.w) << 16);
    *(uint2*)(z1n + (size_t)row * DIM + lane * 4) = pk;

    if (lane == 0) {
        sq[row] = s1 / (m1 * m1);                       // ||z1n||^2 (≈1)
        float s_pos = logf(expf(-dp * 0.5f) + 1e-8f) + 1.0f;
        atomicAdd(&acc[1], (double)s_pos);
    }
}

// ---------------------------------------------------------------------------
// Kernel 2: fused Z·Z^T + exp-sum epilogue over upper block-triangle.
// 128x128 tile per block, 4 waves (2x2), 16x16x32 bf16 MFMA, K chunked by 64.
// ---------------------------------------------------------------------------
__global__ __launch_bounds__(256) void pair_kernel(
    const unsigned short* __restrict__ z1n, const float* __restrict__ sq,
    double* __restrict__ acc) {

    int bi = blockIdx.y, bj = blockIdx.x;
    if (bj < bi) return;                // symmetric: upper triangle only

    __shared__ unsigned short A[128][72];   // +8 pad: stride 144B = 36 dwords
    __shared__ unsigned short B[128][72];
    __shared__ float red[4];

    int tid  = threadIdx.x;
    int wave = tid >> 6, lane = tid & 63;
    int wr = wave >> 1, wc = wave & 1;
    int quad = lane >> 4, colL = lane & 15;

    f32x4 accf[4][4] = {};

    for (int kc = 0; kc < 4; ++kc) {
        __syncthreads();
        // stage 128x64 bf16 panels: 8 lanes x 16B per row, 32 rows per pass
        int r0 = tid >> 3, c8 = tid & 7;
        #pragma unroll
        for (int p = 0; p < 4; ++p) {
            int r = p * 32 + r0;
            const uint4 va = *(const uint4*)(z1n + (size_t)(bi*128 + r) * DIM + kc*64 + c8*8);
            *(uint4*)&A[r][c8*8] = va;
            const uint4 vb = *(const uint4*)(z1n + (size_t)(bj*128 + r) * DIM + kc*64 + c8*8);
            *(uint4*)&B[r][c8*8] = vb;
        }
        __syncthreads();

        #pragma unroll
        for (int kk = 0; kk < 2; ++kk) {
            int k0 = kk * 32 + quad * 8;
            short8 af[4], bf[4];
            #pragma unroll
            for (int m = 0; m < 4; ++m)
                af[m] = *(const short8*)&A[wr*64 + m*16 + colL][k0];
            #pragma unroll
            for (int n = 0; n < 4; ++n)
                bf[n] = *(const short8*)&B[wc*64 + n*16 + colL][k0];
            #pragma unroll
            for (int m = 0; m < 4; ++m)
                #pragma unroll
                for (int n = 0; n < 4; ++n)
                    accf[m][n] = __builtin_amdgcn_mfma_f32_16x16x32_bf16(
                        af[m], bf[n], accf[m][n], 0, 0, 0);
        }
    }

    // epilogue: term = exp(-max(sq_i + sq_j - 2*dot, 0) * 0.5), skip i==j
    float local = 0.0f;
    float sqj[4];
    #pragma unroll
    for (int n = 0; n < 4; ++n)
        sqj[n] = sq[bj*128 + wc*64 + n*16 + colL];

    #pragma unroll
    for (int m = 0; m < 4; ++m) {
        #pragma unroll
        for (int reg = 0; reg < 4; ++reg) {
            int i = bi*128 + wr*64 + m*16 + quad*4 + reg;
            float sqi = sq[i];
            #pragma unroll
            for (int n = 0; n < 4; ++n) {
                int j = bj*128 + wc*64 + n*16 + colL;
                if (i == j) continue;
                float d2 = fmaxf(sqi + sqj[n] - 2.0f * accf[m][n][reg], 0.0f);
                local += expf(-d2 * 0.5f);
            }
        }
    }
    if (bi != bj) local *= 2.0f;        // account for mirrored block

    #pragma unroll
    for (int off = 32; off; off >>= 1) local += __shfl_down(local, off);
    if (lane == 0) red[wave] = local;
    __syncthreads();
    if (tid == 0)
        atomicAdd(&acc[0], (double)(red[0] + red[1] + red[2] + red[3]));
}

// ---------------------------------------------------------------------------
// Kernel 3: finalize
// ---------------------------------------------------------------------------
__global__ void finalize_kernel(const double* __restrict__ acc, float* __restrict__ out) {
    double mean_star = acc[0] / (8192.0 * 8191.0) + 1e-8;
    out[0] = (float)(-acc[1] / 8192.0 + 1.5 * mean_star);
}

extern "C" void kernel_launch(void* const* d_in, const int* in_sizes, int n_in,
                              void* d_out, int out_size, void* d_ws, size_t ws_size,
                              hipStream_t stream) {
    const float* z1 = (const float*)d_in[0];
    const float* z2 = (const float*)d_in[1];
    float* out = (float*)d_out;

    char* ws = (char*)d_ws;
    double* acc = (double*)ws;                              // 16 B
    float* sq = (float*)(ws + 16);                          // 32 KB
    unsigned short* z1n = (unsigned short*)(ws + 16 + N_ROWS * 4); // 4 MB bf16

    hipMemsetAsync(d_ws, 0, 16, stream);                    // zero accumulators

    norm_kernel<<<N_ROWS / 4, 256, 0, stream>>>(z1, z2, z1n, sq, acc);
    pair_kernel<<<dim3(64, 64), 256, 0, stream>>>(z1n, sq, acc);
    finalize_kernel<<<1, 1, 0, stream>>>(acc, out);
}

// Round 2
// 119.696 us; speedup vs baseline: 1.9083x; 1.9083x over previous
//
#include <hip/hip_runtime.h>
#include <hip/hip_bf16.h>

// FMICLLoss: out = -mean(s_pos) + ALPHA * ( sum_{i!=j} exp(-d2_ij/2) / (N(N-1)) + EPS )
// N=8192, D=256, SIGMA=1 (inv2s2=0.5), ALPHA=1.5, EPS=1e-8, NORM_EPS=1e-12.
//
// Round 2: removed ALL contended double atomics (norm had 8192, pair had 2080
// same-address f64 atomics @ ~12.7ns serialized = ~100us each). Blocks now
// write fp32 partials to private ws slots; finalize reduces in double.

#define N_ROWS 8192
#define DIM    256

typedef __attribute__((ext_vector_type(8))) short short8;
typedef __attribute__((ext_vector_type(4))) float f32x4;

__device__ inline unsigned short f2bf(float f) {
    unsigned u = __float_as_uint(f);
    unsigned r = u + 0x7FFF + ((u >> 16) & 1);   // round-to-nearest-even
    return (unsigned short)(r >> 16);
}

// ---------------------------------------------------------------------------
// Kernel 1: row-normalize z1,z2; write z1n (bf16) + sq[i]; per-block s_pos partial.
// One wave per row (4 rows / 256-thread block). No atomics.
// ---------------------------------------------------------------------------
__global__ __launch_bounds__(256) void norm_kernel(
    const float* __restrict__ z1, const float* __restrict__ z2,
    unsigned short* __restrict__ z1n, float* __restrict__ sq,
    float* __restrict__ spos_part) {

    int tid  = threadIdx.x;
    int wave = tid >> 6, lane = tid & 63;
    int row  = blockIdx.x * 4 + wave;

    const float4 a = *(const float4*)(z1 + (size_t)row * DIM + lane * 4);
    const float4 b = *(const float4*)(z2 + (size_t)row * DIM + lane * 4);

    float s1 = a.x*a.x + a.y*a.y + a.z*a.z + a.w*a.w;
    float s2 = b.x*b.x + b.y*b.y + b.z*b.z + b.w*b.w;
    #pragma unroll
    for (int off = 32; off; off >>= 1) {
        s1 += __shfl_xor(s1, off);
        s2 += __shfl_xor(s2, off);
    }
    float m1 = fmaxf(sqrtf(s1), 1e-12f);
    float m2 = fmaxf(sqrtf(s2), 1e-12f);

    float4 an = make_float4(a.x/m1, a.y/m1, a.z/m1, a.w/m1);
    float4 bn = make_float4(b.x/m2, b.y/m2, b.z/m2, b.w/m2);

    // positive-pair distance
    float dx = an.x - bn.x, dy = an.y - bn.y, dz = an.z - bn.z, dw = an.w - bn.w;
    float dp = dx*dx + dy*dy + dz*dz + dw*dw;
    #pragma unroll
    for (int off = 32; off; off >>= 1) dp += __shfl_xor(dp, off);

    // write bf16 normalized z1 row (8B per lane)
    uint2 pk;
    pk.x = (unsigned)f2bf(an.x) | ((unsigned)f2bf(an.y) << 16);
    pk.y = (unsigned)f2bf(an.z) | ((unsigned)f2bf(an.w) << 16);
    *(uint2*)(z1n + (size_t)row * DIM + lane * 4) = pk;

    __shared__ float sp[4];
    if (lane == 0) {
        sq[row] = s1 / (m1 * m1);                       // ||z1n||^2 (≈1)
        sp[wave] = logf(expf(-dp * 0.5f) + 1e-8f) + 1.0f;  // s_pos
    }
    __syncthreads();
    if (tid == 0)
        spos_part[blockIdx.x] = sp[0] + sp[1] + sp[2] + sp[3];
}

// ---------------------------------------------------------------------------
// Kernel 2: fused Z·Z^T + exp-sum epilogue over upper block-triangle.
// 128x128 tile per block, 4 waves (2x2), 16x16x32 bf16 MFMA, K chunked by 64.
// Writes one fp32 partial per block (lower triangle writes 0 — ws is poisoned).
// ---------------------------------------------------------------------------
__global__ __launch_bounds__(256) void pair_kernel(
    const unsigned short* __restrict__ z1n, const float* __restrict__ sq,
    float* __restrict__ negp_part) {

    int bi = blockIdx.y, bj = blockIdx.x;
    int slot = bi * 64 + bj;
    if (bj < bi) {                      // symmetric: upper triangle only
        if (threadIdx.x == 0) negp_part[slot] = 0.0f;
        return;
    }

    __shared__ unsigned short A[128][72];   // +8 pad: stride 144B = 36 dwords
    __shared__ unsigned short B[128][72];
    __shared__ float red[4];

    int tid  = threadIdx.x;
    int wave = tid >> 6, lane = tid & 63;
    int wr = wave >> 1, wc = wave & 1;
    int quad = lane >> 4, colL = lane & 15;

    f32x4 accf[4][4] = {};

    for (int kc = 0; kc < 4; ++kc) {
        __syncthreads();
        // stage 128x64 bf16 panels: 8 lanes x 16B per row, 32 rows per pass
        int r0 = tid >> 3, c8 = tid & 7;
        #pragma unroll
        for (int p = 0; p < 4; ++p) {
            int r = p * 32 + r0;
            const uint4 va = *(const uint4*)(z1n + (size_t)(bi*128 + r) * DIM + kc*64 + c8*8);
            *(uint4*)&A[r][c8*8] = va;
            const uint4 vb = *(const uint4*)(z1n + (size_t)(bj*128 + r) * DIM + kc*64 + c8*8);
            *(uint4*)&B[r][c8*8] = vb;
        }
        __syncthreads();

        #pragma unroll
        for (int kk = 0; kk < 2; ++kk) {
            int k0 = kk * 32 + quad * 8;
            short8 af[4], bf[4];
            #pragma unroll
            for (int m = 0; m < 4; ++m)
                af[m] = *(const short8*)&A[wr*64 + m*16 + colL][k0];
            #pragma unroll
            for (int n = 0; n < 4; ++n)
                bf[n] = *(const short8*)&B[wc*64 + n*16 + colL][k0];
            #pragma unroll
            for (int m = 0; m < 4; ++m)
                #pragma unroll
                for (int n = 0; n < 4; ++n)
                    accf[m][n] = __builtin_amdgcn_mfma_f32_16x16x32_bf16(
                        af[m], bf[n], accf[m][n], 0, 0, 0);
        }
    }

    // epilogue: term = exp(-max(sq_i + sq_j - 2*dot, 0) * 0.5), skip i==j
    float local = 0.0f;
    float sqj[4];
    #pragma unroll
    for (int n = 0; n < 4; ++n)
        sqj[n] = sq[bj*128 + wc*64 + n*16 + colL];

    #pragma unroll
    for (int m = 0; m < 4; ++m) {
        #pragma unroll
        for (int reg = 0; reg < 4; ++reg) {
            int i = bi*128 + wr*64 + m*16 + quad*4 + reg;
            float sqi = sq[i];
            #pragma unroll
            for (int n = 0; n < 4; ++n) {
                int j = bj*128 + wc*64 + n*16 + colL;
                float d2 = fmaxf(sqi + sqj[n] - 2.0f * accf[m][n][reg], 0.0f);
                float e = __expf(-d2 * 0.5f);
                local += (i == j) ? 0.0f : e;
            }
        }
    }
    if (bi != bj) local *= 2.0f;        // account for mirrored block

    #pragma unroll
    for (int off = 32; off; off >>= 1) local += __shfl_down(local, off);
    if (lane == 0) red[wave] = local;
    __syncthreads();
    if (tid == 0)
        negp_part[slot] = red[0] + red[1] + red[2] + red[3];
}

// ---------------------------------------------------------------------------
// Kernel 3: finalize — reduce partials in double, emit scalar.
// ---------------------------------------------------------------------------
__global__ __launch_bounds__(256) void finalize_kernel(
    const float* __restrict__ spos_part, const float* __restrict__ negp_part,
    float* __restrict__ out) {

    int tid = threadIdx.x;
    double s = 0.0, ng = 0.0;
    for (int i = tid; i < 2048; i += 256) s  += (double)spos_part[i];
    for (int i = tid; i < 4096; i += 256) ng += (double)negp_part[i];

    #pragma unroll
    for (int off = 32; off; off >>= 1) {
        s  += __shfl_xor(s,  off);
        ng += __shfl_xor(ng, off);
    }
    __shared__ double sd[4], nd[4];
    int wave = tid >> 6, lane = tid & 63;
    if (lane == 0) { sd[wave] = s; nd[wave] = ng; }
    __syncthreads();
    if (tid == 0) {
        double st = sd[0] + sd[1] + sd[2] + sd[3];
        double nt = nd[0] + nd[1] + nd[2] + nd[3];
        double mean_star = nt / (8192.0 * 8191.0) + 1e-8;
        out[0] = (float)(-st / 8192.0 + 1.5 * mean_star);
    }
}

extern "C" void kernel_launch(void* const* d_in, const int* in_sizes, int n_in,
                              void* d_out, int out_size, void* d_ws, size_t ws_size,
                              hipStream_t stream) {
    const float* z1 = (const float*)d_in[0];
    const float* z2 = (const float*)d_in[1];
    float* out = (float*)d_out;

    char* ws = (char*)d_ws;
    float* sq            = (float*)ws;                                   // 32 KB
    unsigned short* z1n  = (unsigned short*)(ws + N_ROWS * 4);           // 4 MB bf16
    float* spos_part     = (float*)(ws + N_ROWS * 4 + N_ROWS * DIM * 2); // 8 KB
    float* negp_part     = spos_part + 2048;                             // 16 KB

    norm_kernel<<<N_ROWS / 4, 256, 0, stream>>>(z1, z2, z1n, sq, spos_part);
    pair_kernel<<<dim3(64, 64), 256, 0, stream>>>(z1n, sq, negp_part);
    finalize_kernel<<<1, 256, 0, stream>>>(spos_part, negp_part, out);
}

// Round 3
// 93.223 us; speedup vs baseline: 2.4503x; 1.2840x over previous
//
#include <hip/hip_runtime.h>
#include <hip/hip_bf16.h>

// FMICLLoss: out = -mean(s_pos) + ALPHA * ( sum_{i!=j} exp(-d2_ij/2) / (N(N-1)) + EPS )
// N=8192, D=256, SIGMA=1 (inv2s2=0.5), ALPHA=1.5, EPS=1e-8, NORM_EPS=1e-12.
//
// Round 3: pair_kernel rebuilt on the m97 structure:
//  - global_load_lds width=16 DMA staging (no VGPR round-trip, no ds_write)
//  - XOR swizzle (stored_cb = cb ^ (row&7)) applied on the GLOBAL source addr,
//    so DMA's lane-ordered LDS writes land where the swizzled reader expects
//    -> conflict-free ds_read_b128 with zero padding
//  - triangular 2080-block grid (no dead lower-triangle dispatches)
//  - epilogue: term = exp2(min(dot*log2e - h_i - h_j, 0)), h precomputed

#define N_ROWS 8192
#define DIM    256
#define LOG2E  1.4426950408889634f

typedef __attribute__((ext_vector_type(8))) short short8;
typedef __attribute__((ext_vector_type(4))) float f32x4;

#define GLDS16(gptr, lptr) \
  __builtin_amdgcn_global_load_lds((const __attribute__((address_space(1))) void*)(gptr), \
                                   (__attribute__((address_space(3))) void*)(lptr), 16, 0, 0)

__device__ inline unsigned short f2bf(float f) {
    unsigned u = __float_as_uint(f);
    unsigned r = u + 0x7FFF + ((u >> 16) & 1);   // round-to-nearest-even
    return (unsigned short)(r >> 16);
}

// ---------------------------------------------------------------------------
// Kernel 1: row-normalize z1,z2; write z1n (bf16) + hl[i]=0.5*log2e*||z1n_i||^2;
// per-block s_pos partial. One wave per row (4 rows / 256-thread block).
// ---------------------------------------------------------------------------
__global__ __launch_bounds__(256) void norm_kernel(
    const float* __restrict__ z1, const float* __restrict__ z2,
    unsigned short* __restrict__ z1n, float* __restrict__ hl,
    float* __restrict__ spos_part) {

    int tid  = threadIdx.x;
    int wave = tid >> 6, lane = tid & 63;
    int row  = blockIdx.x * 4 + wave;

    const float4 a = *(const float4*)(z1 + (size_t)row * DIM + lane * 4);
    const float4 b = *(const float4*)(z2 + (size_t)row * DIM + lane * 4);

    float s1 = a.x*a.x + a.y*a.y + a.z*a.z + a.w*a.w;
    float s2 = b.x*b.x + b.y*b.y + b.z*b.z + b.w*b.w;
    #pragma unroll
    for (int off = 32; off; off >>= 1) {
        s1 += __shfl_xor(s1, off);
        s2 += __shfl_xor(s2, off);
    }
    float m1 = fmaxf(sqrtf(s1), 1e-12f);
    float m2 = fmaxf(sqrtf(s2), 1e-12f);

    float4 an = make_float4(a.x/m1, a.y/m1, a.z/m1, a.w/m1);
    float4 bn = make_float4(b.x/m2, b.y/m2, b.z/m2, b.w/m2);

    // positive-pair distance
    float dx = an.x - bn.x, dy = an.y - bn.y, dz = an.z - bn.z, dw = an.w - bn.w;
    float dp = dx*dx + dy*dy + dz*dz + dw*dw;
    #pragma unroll
    for (int off = 32; off; off >>= 1) dp += __shfl_xor(dp, off);

    // write bf16 normalized z1 row (8B per lane)
    uint2 pk;
    pk.x = (unsigned)f2bf(an.x) | ((unsigned)f2bf(an.y) << 16);
    pk.y = (unsigned)f2bf(an.z) | ((unsigned)f2bf(an.w) << 16);
    *(uint2*)(z1n + (size_t)row * DIM + lane * 4) = pk;

    __shared__ float sp[4];
    if (lane == 0) {
        float sqn = s1 / (m1 * m1);                      // ||z1n||^2 (fp32-exact)
        hl[row] = 0.5f * LOG2E * sqn;
        sp[wave] = logf(expf(-dp * 0.5f) + 1e-8f) + 1.0f;  // s_pos
    }
    __syncthreads();
    if (tid == 0)
        spos_part[blockIdx.x] = sp[0] + sp[1] + sp[2] + sp[3];
}

// ---------------------------------------------------------------------------
// Kernel 2: fused Z·Z^T + exp-sum epilogue, upper block-triangle only.
// 128x128 tile / block, 4 waves (2x2), 16x16x32 bf16 MFMA, K chunked by 64.
// DMA staging via global_load_lds(16B), XOR-swizzled LDS, no padding.
// ---------------------------------------------------------------------------
__global__ __launch_bounds__(256) void pair_kernel(
    const unsigned short* __restrict__ z1n, const float* __restrict__ hl,
    float* __restrict__ negp_part) {

    // triangular decode: block t -> (bi, bj), bi <= bj, 2080 blocks
    int t = blockIdx.x;
    int u = 2079 - t;
    int k = (int)((sqrtf(8.0f * (float)u + 1.0f) - 1.0f) * 0.5f);
    while ((k + 1) * (k + 2) / 2 <= u) ++k;
    while (k * (k + 1) / 2 > u) --k;
    int bi = 63 - k;
    int bj = 63 - (u - k * (k + 1) / 2);

    __shared__ unsigned short A[128 * 64];   // 16 KB, chunk-local, XOR-swizzled
    __shared__ unsigned short B[128 * 64];   // 16 KB
    __shared__ float red[4];

    int tid  = threadIdx.x;
    int wave = tid >> 6, lane = tid & 63;
    int wr = wave >> 1, wc = wave & 1;
    int quad = lane >> 4, colL = lane & 15;

    // DMA source addressing: lane l = (rl,cl); row = base+rl, stored cb = cl,
    // so it must fetch logical cb = cl ^ rl  (row&7 == rl for 8-aligned bases)
    int rl = lane >> 3, cl = lane & 7;
    int swz = ((cl ^ rl) << 3);              // shorts
    const unsigned short* gA = z1n + (size_t)(bi * 128 + wave * 32 + rl) * DIM + swz;
    const unsigned short* gB = z1n + (size_t)(bj * 128 + wave * 32 + rl) * DIM + swz;
    unsigned short* lA = &A[(wave * 32) * 64];
    unsigned short* lB = &B[(wave * 32) * 64];

    f32x4 accf[4][4] = {};
    const int rA = (wr * 64 + colL) * 64;    // shorts, af row base (m=0)
    const int rB = (wc * 64 + colL) * 64;
    const int c7 = colL & 7;

    for (int kc = 0; kc < 4; ++kc) {
        __syncthreads();                     // prev chunk's reads done
        #pragma unroll
        for (int q = 0; q < 4; ++q) {        // 8 rows per issue
            GLDS16(gA + kc * 64 + q * 8 * DIM, lA + q * 8 * 64);
            GLDS16(gB + kc * 64 + q * 8 * DIM, lB + q * 8 * 64);
        }
        __syncthreads();                     // drains vmcnt -> DMA data visible

        #pragma unroll
        for (int kk = 0; kk < 2; ++kk) {
            int cb = (((kk * 4 + quad) ^ c7) << 3);   // stored 16B-block, shorts
            short8 af[4], bf[4];
            #pragma unroll
            for (int m = 0; m < 4; ++m)
                af[m] = *(const short8*)&A[rA + m * 1024 + cb];
            #pragma unroll
            for (int n = 0; n < 4; ++n)
                bf[n] = *(const short8*)&B[rB + n * 1024 + cb];
            #pragma unroll
            for (int m = 0; m < 4; ++m)
                #pragma unroll
                for (int n = 0; n < 4; ++n)
                    accf[m][n] = __builtin_amdgcn_mfma_f32_16x16x32_bf16(
                        af[m], bf[n], accf[m][n], 0, 0, 0);
        }
    }

    // epilogue: term = exp2(min(dot*log2e - h_i - h_j, 0)), skip i==j (diag blocks)
    float local = 0.0f;
    float hjn[4];
    #pragma unroll
    for (int n = 0; n < 4; ++n)
        hjn[n] = hl[bj * 128 + wc * 64 + n * 16 + colL];

    if (bi != bj) {
        #pragma unroll
        for (int m = 0; m < 4; ++m) {
            #pragma unroll
            for (int reg = 0; reg < 4; ++reg) {
                float hi = hl[bi * 128 + wr * 64 + m * 16 + quad * 4 + reg];
                #pragma unroll
                for (int n = 0; n < 4; ++n) {
                    float arg = fminf(accf[m][n][reg] * LOG2E - hi - hjn[n], 0.0f);
                    local += __builtin_amdgcn_exp2f(arg);
                }
            }
        }
        local *= 2.0f;                       // mirrored block
    } else {
        #pragma unroll
        for (int m = 0; m < 4; ++m) {
            #pragma unroll
            for (int reg = 0; reg < 4; ++reg) {
                int i = wr * 64 + m * 16 + quad * 4 + reg;
                float hi = hl[bi * 128 + i];
                #pragma unroll
                for (int n = 0; n < 4; ++n) {
                    int j = wc * 64 + n * 16 + colL;
                    float arg = fminf(accf[m][n][reg] * LOG2E - hi - hjn[n], 0.0f);
                    float e = __builtin_amdgcn_exp2f(arg);
                    local += (i == j) ? 0.0f : e;
                }
            }
        }
    }

    #pragma unroll
    for (int off = 32; off; off >>= 1) local += __shfl_down(local, off);
    if (lane == 0) red[wave] = local;
    __syncthreads();
    if (tid == 0)
        negp_part[blockIdx.x] = red[0] + red[1] + red[2] + red[3];
}

// ---------------------------------------------------------------------------
// Kernel 3: finalize — reduce partials in double, emit scalar.
// ---------------------------------------------------------------------------
__global__ __launch_bounds__(256) void finalize_kernel(
    const float* __restrict__ spos_part, const float* __restrict__ negp_part,
    float* __restrict__ out) {

    int tid = threadIdx.x;
    double s = 0.0, ng = 0.0;
    for (int i = tid; i < 2048; i += 256) s  += (double)spos_part[i];
    for (int i = tid; i < 2080; i += 256) ng += (double)negp_part[i];

    #pragma unroll
    for (int off = 32; off; off >>= 1) {
        s  += __shfl_xor(s,  off);
        ng += __shfl_xor(ng, off);
    }
    __shared__ double sd[4], nd[4];
    int wave = tid >> 6, lane = tid & 63;
    if (lane == 0) { sd[wave] = s; nd[wave] = ng; }
    __syncthreads();
    if (tid == 0) {
        double st = sd[0] + sd[1] + sd[2] + sd[3];
        double nt = nd[0] + nd[1] + nd[2] + nd[3];
        double mean_star = nt / (8192.0 * 8191.0) + 1e-8;
        out[0] = (float)(-st / 8192.0 + 1.5 * mean_star);
    }
}

extern "C" void kernel_launch(void* const* d_in, const int* in_sizes, int n_in,
                              void* d_out, int out_size, void* d_ws, size_t ws_size,
                              hipStream_t stream) {
    const float* z1 = (const float*)d_in[0];
    const float* z2 = (const float*)d_in[1];
    float* out = (float*)d_out;

    char* ws = (char*)d_ws;
    float* hl            = (float*)ws;                                   // 32 KB
    unsigned short* z1n  = (unsigned short*)(ws + N_ROWS * 4);           // 4 MB bf16
    float* spos_part     = (float*)(ws + N_ROWS * 4 + N_ROWS * DIM * 2); // 8 KB
    float* negp_part     = spos_part + 2048;                             // 8.3 KB

    norm_kernel<<<N_ROWS / 4, 256, 0, stream>>>(z1, z2, z1n, hl, spos_part);
    pair_kernel<<<2080, 256, 0, stream>>>(z1n, hl, negp_part);
    finalize_kernel<<<1, 256, 0, stream>>>(spos_part, negp_part, out);
}